// Round 8
// baseline (173.185 us; speedup 1.0000x reference)
//
#include <hip/hip_runtime.h>

#define WIDTH 128
#define SLOPE 0.01f
#define SBS 512
#define FBM 32

typedef __attribute__((ext_vector_type(8))) short short8;
typedef __attribute__((ext_vector_type(4))) float f32x4;

__device__ __forceinline__ unsigned short f2bf(float f) {
    unsigned b = __float_as_uint(f);
    b += 0x7FFFu + ((b >> 16) & 1u);   // round-to-nearest-even
    return (unsigned short)(b >> 16);
}
__device__ __forceinline__ float4 upk(uint2 u) {   // 4 bf16 -> 4 f32 (exact)
    float4 r;
    r.x = __uint_as_float(u.x << 16);
    r.y = __uint_as_float(u.x & 0xFFFF0000u);
    r.z = __uint_as_float(u.y << 16);
    r.w = __uint_as_float(u.y & 0xFFFF0000u);
    return r;
}
// monotone bf16(u16) <-> u16 map: unsigned compare == float compare
__device__ __forceinline__ unsigned map16(unsigned x) {
    return (x & 0x8000u) ? (~x & 0xFFFFu) : (x | 0x8000u);
}
__device__ __forceinline__ unsigned short unmap16(unsigned u) {
    return (unsigned short)((u & 0x8000u) ? (u ^ 0x8000u) : (~u & 0xFFFFu));
}
// XOR-swizzled LDS byte offset for row-major [32][512B] A tile (T2/G4)
__device__ __forceinline__ int swz(int lr, int bc) {
    return lr * 512 + (bc ^ ((lr & 7) << 4));
}

// ---------------- prep: xsb = bf16(x_src)  |  hist  |  W fold+transpose ----
__global__ void prep_kernel(const float* __restrict__ x_src,
                            const float* __restrict__ W,
                            const int* __restrict__ e,
                            unsigned short* __restrict__ xsb,
                            unsigned short* __restrict__ Wt,
                            unsigned* __restrict__ counts,
                            int* __restrict__ rank,
                            int NS, int E, int nconv, int nhist) {
    int b = blockIdx.x;
    if (b < nconv) {
        int i = b * 256 + threadIdx.x;          // float4 units over x_src
        if (i < NS * 32) {
            float4 v = reinterpret_cast<const float4*>(x_src)[i];
            ushort4 o;
            o.x = f2bf(v.x); o.y = f2bf(v.y); o.z = f2bf(v.z); o.w = f2bf(v.w);
            *reinterpret_cast<ushort4*>(xsb + (size_t)i * 4) = o;
        }
    } else if (b < nconv + nhist) {
        int i = (b - nconv) * 256 + threadIdx.x;
        if (i < E) {
            int dst = e[E + i];
            rank[i] = (int)atomicAdd(&counts[dst], 1u);
        }
    } else {
        int t = (b - nconv - nhist) * 256 + threadIdx.x;
        if (t < 128 * 64) {
            int n = t & 127, kc = t >> 7;       // k = kc*4+j over 0..255
            ushort4 o;
            unsigned short* op = &o.x;
            #pragma unroll
            for (int j = 0; j < 4; ++j) {
                int k = kc * 4 + j;
                float v;
                if (k < 128) v = W[(size_t)k * 128 + n] + W[(size_t)(k + 128) * 128 + n];
                else         v = -W[(size_t)k * 128 + n];
                op[j] = f2bf(v);
            }
            *reinterpret_cast<ushort4*>(Wt + (size_t)n * 256 + kc * 4) = o;
        }
    }
}

// ---------------- scan + scatter (counting sort by dst) --------------------
__global__ void block_sum_kernel(const unsigned* __restrict__ counts,
                                 unsigned* __restrict__ bsums, int M) {
    int i = blockIdx.x * SBS + threadIdx.x;
    unsigned v = (i < M) ? counts[i] : 0u;
    for (int d = 32; d > 0; d >>= 1) v += __shfl_down(v, d);
    __shared__ unsigned ws[SBS / 64];
    int lane = threadIdx.x & 63, w = threadIdx.x >> 6;
    if (lane == 0) ws[w] = v;
    __syncthreads();
    if (threadIdx.x == 0) {
        unsigned s = 0;
        for (int k = 0; k < SBS / 64; ++k) s += ws[k];
        bsums[blockIdx.x] = s;
    }
}

__global__ void bsum_scan_kernel(const unsigned* __restrict__ bsums,
                                 unsigned* __restrict__ bbase, int NB,
                                 int* __restrict__ offsets, int M) {
    __shared__ unsigned s[256];
    int t = threadIdx.x;
    unsigned v = (t < NB) ? bsums[t] : 0u;
    s[t] = v;
    __syncthreads();
    for (int off = 1; off < 256; off <<= 1) {
        unsigned n = (t >= off) ? s[t - off] : 0u;
        __syncthreads();
        s[t] += n;
        __syncthreads();
    }
    if (t < NB) bbase[t] = s[t] - v;
    if (t == 255) offsets[M] = (int)s[255];
}

__global__ void scan_final_kernel(const unsigned* __restrict__ counts,
                                  const unsigned* __restrict__ bbase,
                                  int* __restrict__ offsets, int M) {
    int b = blockIdx.x, t = threadIdx.x;
    int i = b * SBS + t;
    unsigned c = (i < M) ? counts[i] : 0u;
    unsigned v = c;
    int lane = t & 63, w = t >> 6;
    for (int d = 1; d < 64; d <<= 1) {
        unsigned n = __shfl_up(v, d);
        if (lane >= d) v += n;
    }
    __shared__ unsigned ws[SBS / 64];
    if (lane == 63) ws[w] = v;
    __syncthreads();
    unsigned wbase = 0;
    for (int k = 0; k < w; ++k) wbase += ws[k];
    if (i < M) offsets[i] = (int)(bbase[b] + wbase + v - c);
}

// pack src (17b) | dst-local-row (5b, FBM=32) into csr entry
__global__ void scatter_kernel(const int* __restrict__ e,
                               const int* __restrict__ offsets,
                               const int* __restrict__ rank,
                               unsigned* __restrict__ csr, int E) {
    int i = blockIdx.x * blockDim.x + threadIdx.x;
    if (i < E) {
        int dst = e[E + i];
        unsigned pack = (unsigned)e[i] | ((unsigned)(dst & (FBM - 1)) << 20);
        csr[offsets[dst] + rank[i]] = pack;
    }
}

// ---- per-edge gather: 4 conflict-free LDS atomic mins (cols cl+32j) -------
template<int XSB>
__device__ __forceinline__ void edge_min(const float* __restrict__ x_src,
                                         const unsigned short* __restrict__ xsb,
                                         unsigned pack, int cl,
                                         unsigned* __restrict__ minbuf) {
    int src = (int)(pack & 0xFFFFFu);
    int lr  = (int)(pack >> 20);
    unsigned m0, m1, m2, m3;
    if (XSB) {
        const unsigned short* p = xsb + (size_t)src * WIDTH + cl;
        m0 = map16(p[0]);
        m1 = map16(p[32]);
        m2 = map16(p[64]);
        m3 = map16(p[96]);
    } else {
        const float* p = x_src + (size_t)src * WIDTH + cl;
        m0 = map16(f2bf(p[0]));
        m1 = map16(f2bf(p[32]));
        m2 = map16(f2bf(p[64]));
        m3 = map16(f2bf(p[96]));
    }
    unsigned* row = minbuf + lr * WIDTH + cl;
    atomicMin(row + 0,  m0);   // ds_min_u32, fire-and-forget
    atomicMin(row + 32, m1);
    atomicMin(row + 64, m2);
    atomicMin(row + 96, m3);
}

// ---------------- Fused: edge-parallel LDS-atomic min + MFMA GEMM ----------
// Block = 32 rows, 4 waves. A = [bf16(x_dst) | mn] in XOR-swizzled LDS.
// h^T = W't * A^T ; out = xb + lrelu(h + b).   M % 32 == 0.
template<int XSB>
__global__ __launch_bounds__(256, 4) void fused_kernel(
        const float* __restrict__ x_src,
        const unsigned short* __restrict__ xsb,
        const float* __restrict__ x_dst,
        const int* __restrict__ offsets,
        const unsigned* __restrict__ csr,
        const unsigned short* __restrict__ Wt,
        const float* __restrict__ bias,
        float* __restrict__ out, int M) {
    __shared__ __align__(16) unsigned short At[FBM * 256];   // 16 KB
    __shared__ __align__(16) unsigned minbuf[FBM * WIDTH];   // 16 KB
    char* Ab = reinterpret_cast<char*>(At);
    int tid = threadIdx.x;
    int lane = tid & 63;
    int wv = tid >> 6;
    int blockRow = blockIdx.x * FBM;

    // ---- phase 0: init minbuf to sentinel + stage xb into A[:,0:128] ----
    {
        uint4* mb4 = reinterpret_cast<uint4*>(minbuf);   // 1024 uint4
        #pragma unroll
        for (int i = 0; i < 4; ++i)
            mb4[tid + 256 * i] = make_uint4(~0u, ~0u, ~0u, ~0u);
    }
    #pragma unroll
    for (int i = 0; i < 4; ++i) {
        int u = tid + 256 * i;              // ushort4 units (1024 total)
        int lr = u >> 5, c4 = u & 31;
        float4 v = reinterpret_cast<const float4*>(x_dst)[(size_t)(blockRow + lr) * 32 + c4];
        ushort4 o;
        o.x = f2bf(v.x); o.y = f2bf(v.y); o.z = f2bf(v.z); o.w = f2bf(v.w);
        *reinterpret_cast<ushort4*>(Ab + swz(lr, c4 * 8)) = o;
    }
    __syncthreads();

    // ---- phase 1: edge-parallel gather + LDS atomic min ----
    // clamped-duplicate edges: no branches, duplicates idempotent for min
    int ebeg = offsets[blockRow];
    int eend = offsets[blockRow + FBM];
    int half = lane >> 5, cl = lane & 31;
    int lim = eend - 1;
    if (eend > ebeg) {
        #pragma unroll 2
        for (int i = ebeg + wv * 4; i < eend; i += 16) {
            unsigned p0 = csr[min(i + half, lim)];
            unsigned p1 = csr[min(i + 2 + half, lim)];
            edge_min<XSB>(x_src, xsb, p0, cl, minbuf);
            edge_min<XSB>(x_src, xsb, p1, cl, minbuf);
        }
    }
    __syncthreads();

    // ---- phase 2: minbuf -> A[:,128:256] (sentinel => xb passthrough) ----
    {
        int r = tid >> 3;                   // 0..31
        int c0 = (tid & 7) * 16;
        #pragma unroll
        for (int k = 0; k < 4; ++k) {
            int c = c0 + k * 4;
            unsigned u0 = minbuf[r * WIDTH + c + 0];
            unsigned u1 = minbuf[r * WIDTH + c + 1];
            unsigned u2 = minbuf[r * WIDTH + c + 2];
            unsigned u3 = minbuf[r * WIDTH + c + 3];
            ushort4 xb = *reinterpret_cast<const ushort4*>(Ab + swz(r, c * 2));
            ushort4 o;
            o.x = (u0 <= 0xFFFFu) ? unmap16(u0) : xb.x;  // empty: mn:=xb => h=xb@W0
            o.y = (u1 <= 0xFFFFu) ? unmap16(u1) : xb.y;
            o.z = (u2 <= 0xFFFFu) ? unmap16(u2) : xb.z;
            o.w = (u3 <= 0xFFFFu) ? unmap16(u3) : xb.w;
            *reinterpret_cast<ushort4*>(Ab + swz(r, 256 + c * 2)) = o;
        }
    }
    __syncthreads();

    // ---- phase 3: MFMA GEMM, A from LDS, B (folded W') from L2 ----
    int l15 = lane & 15;
    int q = lane >> 4;
    int ncol0 = wv * 32;

    f32x4 acc[2][2];
    #pragma unroll
    for (int t = 0; t < 2; ++t) {
        acc[t][0] = (f32x4){0.f, 0.f, 0.f, 0.f};
        acc[t][1] = (f32x4){0.f, 0.f, 0.f, 0.f};
    }
    size_t b0off = (size_t)(ncol0 + l15) * 256;
    size_t b1off = (size_t)(ncol0 + 16 + l15) * 256;

    #pragma unroll
    for (int s = 0; s < 8; ++s) {
        int koff = s * 32 + q * 8;               // bf16 elements
        short8 b0 = *reinterpret_cast<const short8*>(Wt + b0off + koff);
        short8 b1 = *reinterpret_cast<const short8*>(Wt + b1off + koff);
        #pragma unroll
        for (int t = 0; t < 2; ++t) {
            int lr = t * 16 + l15;
            short8 a = *reinterpret_cast<const short8*>(Ab + swz(lr, koff * 2));
            // swapped operands: C col(lane&15)=out row, C row(q*4+reg)=out col
            acc[t][0] = __builtin_amdgcn_mfma_f32_16x16x32_bf16(b0, a, acc[t][0], 0, 0, 0);
            acc[t][1] = __builtin_amdgcn_mfma_f32_16x16x32_bf16(b1, a, acc[t][1], 0, 0, 0);
        }
    }

    float4 bi[2];
    bi[0] = *reinterpret_cast<const float4*>(bias + ncol0 + q * 4);
    bi[1] = *reinterpret_cast<const float4*>(bias + ncol0 + 16 + q * 4);
    #pragma unroll
    for (int t = 0; t < 2; ++t) {
        int lr = t * 16 + l15;
        int row = blockRow + lr;                 // M % 32 == 0: always valid
        #pragma unroll
        for (int u = 0; u < 2; ++u) {
            int col = ncol0 + u * 16 + q * 4;
            uint2 xu = *reinterpret_cast<const uint2*>(Ab + swz(lr, col * 2));
            float4 xb = upk(xu);
            float4 o;
            float h;
            h = acc[t][u][0] + bi[u].x; o.x = xb.x + (h > 0.f ? h : SLOPE * h);
            h = acc[t][u][1] + bi[u].y; o.y = xb.y + (h > 0.f ? h : SLOPE * h);
            h = acc[t][u][2] + bi[u].z; o.z = xb.z + (h > 0.f ? h : SLOPE * h);
            h = acc[t][u][3] + bi[u].w; o.w = xb.w + (h > 0.f ? h : SLOPE * h);
            *reinterpret_cast<float4*>(out + (size_t)row * 128 + col) = o;
        }
    }
}

extern "C" void kernel_launch(void* const* d_in, const int* in_sizes, int n_in,
                              void* d_out, int out_size, void* d_ws, size_t ws_size,
                              hipStream_t stream) {
    const float* x_src = (const float*)d_in[0];
    const float* x_dst = (const float*)d_in[1];
    const int*   e     = (const int*)d_in[2];
    const float* W     = (const float*)d_in[3];
    const float* bias  = (const float*)d_in[4];
    float* out = (float*)d_out;

    int NS = in_sizes[0] / WIDTH;   // 100000 src nodes
    int E  = in_sizes[2] / 2;       // 800000
    int M  = in_sizes[1] / WIDTH;   // 100000 dst nodes
    int NB = (M + SBS - 1) / SBS;   // 196 (<= 256)

    // ws: xsb bf16[NS*128] | Wt bf16[128*256] | counts[M] | offsets[M+1] |
    //     rank[E] | csr[E] | bsums[NB] | bbase[NB]    (~33 MB)
    unsigned short* xsb = (unsigned short*)d_ws;
    unsigned short* Wt  = xsb + (size_t)NS * WIDTH;
    unsigned* counts  = (unsigned*)(Wt + 128 * 256);
    int*      offsets = (int*)(counts + M);
    int*      rank    = offsets + (M + 1);
    unsigned* csr     = (unsigned*)(rank + E);
    unsigned* bsums   = (unsigned*)(csr + E);
    unsigned* bbase   = bsums + NB;
    size_t need = (char*)(bbase + NB) - (char*)d_ws;
    int use_xsb = (ws_size >= need) ? 1 : 0;
    if (!use_xsb) {   // fallback: no xsb; shift layout to skip it
        Wt = (unsigned short*)d_ws;
        counts  = (unsigned*)(Wt + 128 * 256);
        offsets = (int*)(counts + M);
        rank    = offsets + (M + 1);
        csr     = (unsigned*)(rank + E);
        bsums   = (unsigned*)(csr + E);
        bbase   = bsums + NB;
    }

    hipMemsetAsync(counts, 0, (size_t)M * sizeof(unsigned), stream);

    int nconv = use_xsb ? (NS * 32 + 255) / 256 : 0;
    int nhist = (E + 255) / 256;
    int nwt   = (128 * 64 + 255) / 256;
    prep_kernel<<<nconv + nhist + nwt, 256, 0, stream>>>(x_src, W, e, xsb, Wt,
                                                         counts, rank, NS, E,
                                                         nconv, nhist);
    block_sum_kernel<<<NB, SBS, 0, stream>>>(counts, bsums, M);
    bsum_scan_kernel<<<1, 256, 0, stream>>>(bsums, bbase, NB, offsets, M);
    scan_final_kernel<<<NB, SBS, 0, stream>>>(counts, bbase, offsets, M);
    scatter_kernel<<<(E + 255) / 256, 256, 0, stream>>>(e, offsets, rank, csr, E);

    int fblocks = (M + FBM - 1) / FBM;   // 3125
    if (use_xsb)
        fused_kernel<1><<<fblocks, 256, 0, stream>>>(x_src, xsb, x_dst, offsets,
                                                     csr, Wt, bias, out, M);
    else
        fused_kernel<0><<<fblocks, 256, 0, stream>>>(x_src, xsb, x_dst, offsets,
                                                     csr, Wt, bias, out, M);
}

// Round 9
// 160.121 us; speedup vs baseline: 1.0816x; 1.0816x over previous
//
#include <hip/hip_runtime.h>

#define WIDTH 128
#define SLOPE 0.01f
#define SBS 512
#define FBM 64

typedef __attribute__((ext_vector_type(8))) short short8;
typedef __attribute__((ext_vector_type(4))) float f32x4;

__device__ __forceinline__ unsigned short f2bf(float f) {
    unsigned b = __float_as_uint(f);
    b += 0x7FFFu + ((b >> 16) & 1u);   // round-to-nearest-even
    return (unsigned short)(b >> 16);
}
__device__ __forceinline__ float4 upk(uint2 u) {   // 4 bf16 -> 4 f32 (exact)
    float4 r;
    r.x = __uint_as_float(u.x << 16);
    r.y = __uint_as_float(u.x & 0xFFFF0000u);
    r.z = __uint_as_float(u.y << 16);
    r.w = __uint_as_float(u.y & 0xFFFF0000u);
    return r;
}
__device__ __forceinline__ float4 fmin4(float4 a, float4 b) {
    return make_float4(fminf(a.x, b.x), fminf(a.y, b.y),
                       fminf(a.z, b.z), fminf(a.w, b.w));
}
// XOR-swizzled LDS byte offset for row-major [64][512B] tile (T2/G4)
__device__ __forceinline__ int swz(int lr, int bc) {
    return lr * 512 + (bc ^ ((lr & 7) << 4));
}

// ---------------- prep: xsb = bf16(x_src)  |  hist  |  W fold+transpose ----
__global__ void prep_kernel(const float* __restrict__ x_src,
                            const float* __restrict__ W,
                            const int* __restrict__ e,
                            unsigned short* __restrict__ xsb,
                            unsigned short* __restrict__ Wt,
                            unsigned* __restrict__ counts,
                            int* __restrict__ rank,
                            int NS, int E, int nconv, int nhist) {
    int b = blockIdx.x;
    if (b < nconv) {
        int i = b * 256 + threadIdx.x;          // float4 units over x_src
        if (i < NS * 32) {
            float4 v = reinterpret_cast<const float4*>(x_src)[i];
            ushort4 o;
            o.x = f2bf(v.x); o.y = f2bf(v.y); o.z = f2bf(v.z); o.w = f2bf(v.w);
            *reinterpret_cast<ushort4*>(xsb + (size_t)i * 4) = o;
        }
    } else if (b < nconv + nhist) {
        int i = (b - nconv) * 256 + threadIdx.x;
        if (i < E) {
            int dst = e[E + i];
            rank[i] = (int)atomicAdd(&counts[dst], 1u);
        }
    } else {
        int t = (b - nconv - nhist) * 256 + threadIdx.x;
        if (t < 128 * 64) {
            int n = t & 127, kc = t >> 7;       // k = kc*4+j over 0..255
            ushort4 o;
            unsigned short* op = &o.x;
            #pragma unroll
            for (int j = 0; j < 4; ++j) {
                int k = kc * 4 + j;
                float v;
                if (k < 128) v = W[(size_t)k * 128 + n] + W[(size_t)(k + 128) * 128 + n];
                else         v = -W[(size_t)k * 128 + n];
                op[j] = f2bf(v);
            }
            *reinterpret_cast<ushort4*>(Wt + (size_t)n * 256 + kc * 4) = o;
        }
    }
}

// ---------------- scan + scatter (counting sort by dst) --------------------
__global__ void block_sum_kernel(const unsigned* __restrict__ counts,
                                 unsigned* __restrict__ bsums, int M) {
    int i = blockIdx.x * SBS + threadIdx.x;
    unsigned v = (i < M) ? counts[i] : 0u;
    for (int d = 32; d > 0; d >>= 1) v += __shfl_down(v, d);
    __shared__ unsigned ws[SBS / 64];
    int lane = threadIdx.x & 63, w = threadIdx.x >> 6;
    if (lane == 0) ws[w] = v;
    __syncthreads();
    if (threadIdx.x == 0) {
        unsigned s = 0;
        for (int k = 0; k < SBS / 64; ++k) s += ws[k];
        bsums[blockIdx.x] = s;
    }
}

__global__ void bsum_scan_kernel(const unsigned* __restrict__ bsums,
                                 unsigned* __restrict__ bbase, int NB,
                                 int* __restrict__ offsets, int M) {
    __shared__ unsigned s[256];
    int t = threadIdx.x;
    unsigned v = (t < NB) ? bsums[t] : 0u;
    s[t] = v;
    __syncthreads();
    for (int off = 1; off < 256; off <<= 1) {
        unsigned n = (t >= off) ? s[t - off] : 0u;
        __syncthreads();
        s[t] += n;
        __syncthreads();
    }
    if (t < NB) bbase[t] = s[t] - v;
    if (t == 255) offsets[M] = (int)s[255];
}

__global__ void scan_final_kernel(const unsigned* __restrict__ counts,
                                  const unsigned* __restrict__ bbase,
                                  int* __restrict__ offsets, int M) {
    int b = blockIdx.x, t = threadIdx.x;
    int i = b * SBS + t;
    unsigned c = (i < M) ? counts[i] : 0u;
    unsigned v = c;
    int lane = t & 63, w = t >> 6;
    for (int d = 1; d < 64; d <<= 1) {
        unsigned n = __shfl_up(v, d);
        if (lane >= d) v += n;
    }
    __shared__ unsigned ws[SBS / 64];
    if (lane == 63) ws[w] = v;
    __syncthreads();
    unsigned wbase = 0;
    for (int k = 0; k < w; ++k) wbase += ws[k];
    if (i < M) offsets[i] = (int)(bbase[b] + wbase + v - c);
}

__global__ void scatter_kernel(const int* __restrict__ e,
                               const int* __restrict__ offsets,
                               const int* __restrict__ rank,
                               int* __restrict__ csr, int E) {
    int i = blockIdx.x * blockDim.x + threadIdx.x;
    if (i < E) {
        int dst = e[E + i];
        csr[offsets[dst] + rank[i]] = e[i];
    }
}

// -------- 8-edge gather-min step for one row (2 edges/load, lane halves) ---
template<int XSB>
__device__ __forceinline__ void gstep(const float* xs_f,
                                      const unsigned short* xs_b,
                                      const int* csr, int p, int lim,
                                      int half, int cl, float4& mn) {
    int i0 = csr[min(p + 0, lim)];
    int i1 = csr[min(p + 1, lim)];
    int i2 = csr[min(p + 2, lim)];
    int i3 = csr[min(p + 3, lim)];
    int i4 = csr[min(p + 4, lim)];
    int i5 = csr[min(p + 5, lim)];
    int i6 = csr[min(p + 6, lim)];
    int i7 = csr[min(p + 7, lim)];
    int a0 = half ? i1 : i0;
    int a1 = half ? i3 : i2;
    int a2 = half ? i5 : i4;
    int a3 = half ? i7 : i6;
    float4 w0, w1, w2, w3;
    if (XSB) {
        uint2 u0 = *reinterpret_cast<const uint2*>(xs_b + (size_t)a0 * 128 + cl * 4);
        uint2 u1 = *reinterpret_cast<const uint2*>(xs_b + (size_t)a1 * 128 + cl * 4);
        uint2 u2 = *reinterpret_cast<const uint2*>(xs_b + (size_t)a2 * 128 + cl * 4);
        uint2 u3 = *reinterpret_cast<const uint2*>(xs_b + (size_t)a3 * 128 + cl * 4);
        w0 = upk(u0); w1 = upk(u1); w2 = upk(u2); w3 = upk(u3);
    } else {
        const float4* xs4 = reinterpret_cast<const float4*>(xs_f);
        w0 = xs4[(size_t)a0 * 32 + cl];
        w1 = xs4[(size_t)a1 * 32 + cl];
        w2 = xs4[(size_t)a2 * 32 + cl];
        w3 = xs4[(size_t)a3 * 32 + cl];
    }
    mn = fmin4(mn, fmin4(fmin4(w0, w1), fmin4(w2, w3)));
}

// ---------------- Fused: stage xb + gather-min -> LDS -> MFMA GEMM ---------
// Block = 64 rows, 4 waves. A = [bf16(x_dst) | mn] in XOR-swizzled LDS.
// h^T = W't · A^T ; out = xb + lrelu(h + b).
template<int XSB>
__global__ __launch_bounds__(256, 4) void fused_kernel(
        const float* __restrict__ x_src,
        const unsigned short* __restrict__ xsb,
        const float* __restrict__ x_dst,
        const int* __restrict__ offsets,
        const int* __restrict__ csr,
        const unsigned short* __restrict__ Wt,
        const float* __restrict__ bias,
        float* __restrict__ out, int M) {
    __shared__ unsigned short At[FBM * 256];   // 32 KB
    char* Ab = reinterpret_cast<char*>(At);
    int tid = threadIdx.x;
    int lane = tid & 63;
    int wv = tid >> 6;
    int blockRow = blockIdx.x * FBM;

    // ---- phase 1a: xb = bf16(x_dst) into A[:, 0:128] (coalesced) ----
    #pragma unroll
    for (int i = 0; i < 8; ++i) {
        int u = tid + 256 * i;              // float4 unit
        int lr = u >> 5;                    // 0..63
        int c4 = u & 31;
        int gr = min(blockRow + lr, M - 1);
        float4 v = reinterpret_cast<const float4*>(x_dst)[(size_t)gr * 32 + c4];
        ushort4 o;
        o.x = f2bf(v.x); o.y = f2bf(v.y); o.z = f2bf(v.z); o.w = f2bf(v.w);
        *reinterpret_cast<ushort4*>(Ab + swz(lr, c4 * 8)) = o;
    }
    __syncthreads();

    // ---- phase 1b: gather-min, 16 rows/wave, 4-row groups ----
    // Branch-free first-8 per row (one basic block -> 16 gathers in flight;
    // clamped duplicates are idempotent for min). Tail (deg>8) rare: Poisson(8).
    int half = lane >> 5, cl = lane & 31;
    for (int j = 0; j < 4; ++j) {
        int lrb = wv * 16 + 4 * j;
        int beg0, beg1, beg2, beg3, end0, end1, end2, end3;
        {
            int r = __builtin_amdgcn_readfirstlane(blockRow + lrb);
            beg0 = (r + 0 < M) ? offsets[r + 0] : 0;
            end0 = (r + 0 < M) ? offsets[r + 1] : 0;
            beg1 = (r + 1 < M) ? offsets[r + 1] : 0;
            end1 = (r + 1 < M) ? offsets[r + 2] : 0;
            beg2 = (r + 2 < M) ? offsets[r + 2] : 0;
            end2 = (r + 2 < M) ? offsets[r + 3] : 0;
            beg3 = (r + 3 < M) ? offsets[r + 3] : 0;
            end3 = (r + 3 < M) ? offsets[r + 4] : 0;
        }
        float4 mn0 = make_float4(INFINITY, INFINITY, INFINITY, INFINITY);
        float4 mn1 = mn0, mn2 = mn0, mn3 = mn0;
        // unconditional: all 16 paired-gathers issue in one basic block
        gstep<XSB>(x_src, xsb, csr, beg0, max(end0 - 1, 0), half, cl, mn0);
        gstep<XSB>(x_src, xsb, csr, beg1, max(end1 - 1, 0), half, cl, mn1);
        gstep<XSB>(x_src, xsb, csr, beg2, max(end2 - 1, 0), half, cl, mn2);
        gstep<XSB>(x_src, xsb, csr, beg3, max(end3 - 1, 0), half, cl, mn3);
        // rare tail: rows with deg > 8
        int p0 = beg0 + 8, p1 = beg1 + 8, p2 = beg2 + 8, p3 = beg3 + 8;
        while ((p0 < end0) | (p1 < end1) | (p2 < end2) | (p3 < end3)) {
            if (p0 < end0) { gstep<XSB>(x_src, xsb, csr, p0, end0 - 1, half, cl, mn0); p0 += 8; }
            if (p1 < end1) { gstep<XSB>(x_src, xsb, csr, p1, end1 - 1, half, cl, mn1); p1 += 8; }
            if (p2 < end2) { gstep<XSB>(x_src, xsb, csr, p2, end2 - 1, half, cl, mn2); p2 += 8; }
            if (p3 < end3) { gstep<XSB>(x_src, xsb, csr, p3, end3 - 1, half, cl, mn3); p3 += 8; }
        }
        mn0.x = fminf(mn0.x, __shfl_xor(mn0.x, 32));
        mn0.y = fminf(mn0.y, __shfl_xor(mn0.y, 32));
        mn0.z = fminf(mn0.z, __shfl_xor(mn0.z, 32));
        mn0.w = fminf(mn0.w, __shfl_xor(mn0.w, 32));
        mn1.x = fminf(mn1.x, __shfl_xor(mn1.x, 32));
        mn1.y = fminf(mn1.y, __shfl_xor(mn1.y, 32));
        mn1.z = fminf(mn1.z, __shfl_xor(mn1.z, 32));
        mn1.w = fminf(mn1.w, __shfl_xor(mn1.w, 32));
        mn2.x = fminf(mn2.x, __shfl_xor(mn2.x, 32));
        mn2.y = fminf(mn2.y, __shfl_xor(mn2.y, 32));
        mn2.z = fminf(mn2.z, __shfl_xor(mn2.z, 32));
        mn2.w = fminf(mn2.w, __shfl_xor(mn2.w, 32));
        mn3.x = fminf(mn3.x, __shfl_xor(mn3.x, 32));
        mn3.y = fminf(mn3.y, __shfl_xor(mn3.y, 32));
        mn3.z = fminf(mn3.z, __shfl_xor(mn3.z, 32));
        mn3.w = fminf(mn3.w, __shfl_xor(mn3.w, 32));

        // write pair (0,1): lanes<32 -> row lrb, lanes>=32 -> row lrb+1
        {
            int lr = lrb + half;
            bool has = half ? (end1 > beg1) : (end0 > beg0);
            float4 m = half ? mn1 : mn0;
            ushort4 o;
            if (has) {
                o.x = f2bf(m.x); o.y = f2bf(m.y); o.z = f2bf(m.z); o.w = f2bf(m.w);
            } else {   // empty row: mn := xb  =>  h = xb@W0 exactly
                o = *reinterpret_cast<const ushort4*>(Ab + swz(lr, cl * 8));
            }
            *reinterpret_cast<ushort4*>(Ab + swz(lr, 256 + cl * 8)) = o;
        }
        // write pair (2,3)
        {
            int lr = lrb + 2 + half;
            bool has = half ? (end3 > beg3) : (end2 > beg2);
            float4 m = half ? mn3 : mn2;
            ushort4 o;
            if (has) {
                o.x = f2bf(m.x); o.y = f2bf(m.y); o.z = f2bf(m.z); o.w = f2bf(m.w);
            } else {
                o = *reinterpret_cast<const ushort4*>(Ab + swz(lr, cl * 8));
            }
            *reinterpret_cast<ushort4*>(Ab + swz(lr, 256 + cl * 8)) = o;
        }
    }
    __syncthreads();

    // ---- phase 2: MFMA GEMM, A from LDS, B (folded W') from L2 ----
    int l15 = lane & 15;
    int q = lane >> 4;
    int ncol0 = wv * 32;

    f32x4 acc[4][2];
    #pragma unroll
    for (int t = 0; t < 4; ++t) {
        acc[t][0] = (f32x4){0.f, 0.f, 0.f, 0.f};
        acc[t][1] = (f32x4){0.f, 0.f, 0.f, 0.f};
    }
    size_t b0off = (size_t)(ncol0 + l15) * 256;
    size_t b1off = (size_t)(ncol0 + 16 + l15) * 256;

    #pragma unroll
    for (int s = 0; s < 8; ++s) {
        int koff = s * 32 + q * 8;               // bf16 elements
        short8 b0 = *reinterpret_cast<const short8*>(Wt + b0off + koff);
        short8 b1 = *reinterpret_cast<const short8*>(Wt + b1off + koff);
        #pragma unroll
        for (int t = 0; t < 4; ++t) {
            int lr = t * 16 + l15;
            short8 a = *reinterpret_cast<const short8*>(Ab + swz(lr, koff * 2));
            // swapped operands: C col(lane&15)=out row, C row(q*4+reg)=out col
            acc[t][0] = __builtin_amdgcn_mfma_f32_16x16x32_bf16(b0, a, acc[t][0], 0, 0, 0);
            acc[t][1] = __builtin_amdgcn_mfma_f32_16x16x32_bf16(b1, a, acc[t][1], 0, 0, 0);
        }
    }

    float4 bi[2];
    bi[0] = *reinterpret_cast<const float4*>(bias + ncol0 + q * 4);
    bi[1] = *reinterpret_cast<const float4*>(bias + ncol0 + 16 + q * 4);
    #pragma unroll
    for (int t = 0; t < 4; ++t) {
        int lr = t * 16 + l15;
        int row = blockRow + lr;
        if (row < M) {
            #pragma unroll
            for (int u = 0; u < 2; ++u) {
                int col = ncol0 + u * 16 + q * 4;
                uint2 xu = *reinterpret_cast<const uint2*>(Ab + swz(lr, col * 2));
                float4 xb = upk(xu);
                float4 o;
                float h;
                h = acc[t][u][0] + bi[u].x; o.x = xb.x + (h > 0.f ? h : SLOPE * h);
                h = acc[t][u][1] + bi[u].y; o.y = xb.y + (h > 0.f ? h : SLOPE * h);
                h = acc[t][u][2] + bi[u].z; o.z = xb.z + (h > 0.f ? h : SLOPE * h);
                h = acc[t][u][3] + bi[u].w; o.w = xb.w + (h > 0.f ? h : SLOPE * h);
                *reinterpret_cast<float4*>(out + (size_t)row * 128 + col) = o;
            }
        }
    }
}

extern "C" void kernel_launch(void* const* d_in, const int* in_sizes, int n_in,
                              void* d_out, int out_size, void* d_ws, size_t ws_size,
                              hipStream_t stream) {
    const float* x_src = (const float*)d_in[0];
    const float* x_dst = (const float*)d_in[1];
    const int*   e     = (const int*)d_in[2];
    const float* W     = (const float*)d_in[3];
    const float* bias  = (const float*)d_in[4];
    float* out = (float*)d_out;

    int NS = in_sizes[0] / WIDTH;   // 100000 src nodes
    int E  = in_sizes[2] / 2;       // 800000
    int M  = in_sizes[1] / WIDTH;   // 100000 dst nodes
    int NB = (M + SBS - 1) / SBS;   // 196 (<= 256)

    // ws: xsb bf16[NS*128] | Wt bf16[128*256] | counts[M] | offsets[M+1] |
    //     rank[E] | csr[E] | bsums[NB] | bbase[NB]    (~33 MB)
    unsigned short* xsb = (unsigned short*)d_ws;
    unsigned short* Wt  = xsb + (size_t)NS * WIDTH;
    unsigned* counts  = (unsigned*)(Wt + 128 * 256);
    int*      offsets = (int*)(counts + M);
    int*      rank    = offsets + (M + 1);
    int*      csr     = rank + E;
    unsigned* bsums   = (unsigned*)(csr + E);
    unsigned* bbase   = bsums + NB;
    size_t need = (char*)(bbase + NB) - (char*)d_ws;
    int use_xsb = (ws_size >= need) ? 1 : 0;
    if (!use_xsb) {   // fallback: no xsb; shift layout to skip it
        Wt = (unsigned short*)d_ws;
        counts  = (unsigned*)(Wt + 128 * 256);
        offsets = (int*)(counts + M);
        rank    = offsets + (M + 1);
        csr     = rank + E;
        bsums   = (unsigned*)(csr + E);
        bbase   = bsums + NB;
    }

    hipMemsetAsync(counts, 0, (size_t)M * sizeof(unsigned), stream);

    int nconv = use_xsb ? (NS * 32 + 255) / 256 : 0;
    int nhist = (E + 255) / 256;
    int nwt   = (128 * 64 + 255) / 256;
    prep_kernel<<<nconv + nhist + nwt, 256, 0, stream>>>(x_src, W, e, xsb, Wt,
                                                         counts, rank, NS, E,
                                                         nconv, nhist);
    block_sum_kernel<<<NB, SBS, 0, stream>>>(counts, bsums, M);
    bsum_scan_kernel<<<1, 256, 0, stream>>>(bsums, bbase, NB, offsets, M);
    scan_final_kernel<<<NB, SBS, 0, stream>>>(counts, bbase, offsets, M);
    scatter_kernel<<<(E + 255) / 256, 256, 0, stream>>>(e, offsets, rank, csr, E);

    int fblocks = (M + FBM - 1) / FBM;
    if (use_xsb)
        fused_kernel<1><<<fblocks, 256, 0, stream>>>(x_src, xsb, x_dst, offsets,
                                                     csr, Wt, bias, out, M);
    else
        fused_kernel<0><<<fblocks, 256, 0, stream>>>(x_src, xsb, x_dst, offsets,
                                                     csr, Wt, bias, out, M);
}

// Round 10
// 146.669 us; speedup vs baseline: 1.1808x; 1.0917x over previous
//
#include <hip/hip_runtime.h>

#define WIDTH 128
#define SLOPE 0.01f
#define SBS 512
#define FBM 16
#define ECAP 512

typedef __attribute__((ext_vector_type(8))) short short8;
typedef __attribute__((ext_vector_type(4))) float f32x4;

__device__ __forceinline__ unsigned short f2bf(float f) {
    unsigned b = __float_as_uint(f);
    b += 0x7FFFu + ((b >> 16) & 1u);   // round-to-nearest-even
    return (unsigned short)(b >> 16);
}
__device__ __forceinline__ float4 upk(uint2 u) {   // 4 bf16 -> 4 f32 (exact)
    float4 r;
    r.x = __uint_as_float(u.x << 16);
    r.y = __uint_as_float(u.x & 0xFFFF0000u);
    r.z = __uint_as_float(u.y << 16);
    r.w = __uint_as_float(u.y & 0xFFFF0000u);
    return r;
}
__device__ __forceinline__ void fmin8u(float mn[8], uint4 v) {
    mn[0] = fminf(mn[0], __uint_as_float(v.x << 16));
    mn[1] = fminf(mn[1], __uint_as_float(v.x & 0xFFFF0000u));
    mn[2] = fminf(mn[2], __uint_as_float(v.y << 16));
    mn[3] = fminf(mn[3], __uint_as_float(v.y & 0xFFFF0000u));
    mn[4] = fminf(mn[4], __uint_as_float(v.z << 16));
    mn[5] = fminf(mn[5], __uint_as_float(v.z & 0xFFFF0000u));
    mn[6] = fminf(mn[6], __uint_as_float(v.w << 16));
    mn[7] = fminf(mn[7], __uint_as_float(v.w & 0xFFFF0000u));
}
// XOR-swizzled LDS byte offset for row-major [16][512B] A tile (T2/G4)
__device__ __forceinline__ int swz(int lr, int bc) {
    return lr * 512 + (bc ^ ((lr & 7) << 4));
}

// ---------------- prep: xsb = bf16(x_src)  |  hist  |  W fold+transpose ----
__global__ void prep_kernel(const float* __restrict__ x_src,
                            const float* __restrict__ W,
                            const int* __restrict__ e,
                            unsigned short* __restrict__ xsb,
                            unsigned short* __restrict__ Wt,
                            unsigned* __restrict__ counts,
                            int* __restrict__ rank,
                            int NS, int E, int nconv, int nhist) {
    int b = blockIdx.x;
    if (b < nconv) {
        int i = b * 256 + threadIdx.x;          // float4 units over x_src
        if (i < NS * 32) {
            float4 v = reinterpret_cast<const float4*>(x_src)[i];
            ushort4 o;
            o.x = f2bf(v.x); o.y = f2bf(v.y); o.z = f2bf(v.z); o.w = f2bf(v.w);
            *reinterpret_cast<ushort4*>(xsb + (size_t)i * 4) = o;
        }
    } else if (b < nconv + nhist) {
        int i = (b - nconv) * 256 + threadIdx.x;
        if (i < E) {
            int dst = e[E + i];
            rank[i] = (int)atomicAdd(&counts[dst], 1u);
        }
    } else {
        int t = (b - nconv - nhist) * 256 + threadIdx.x;
        if (t < 128 * 64) {
            int n = t & 127, kc = t >> 7;       // k = kc*4+j over 0..255
            ushort4 o;
            unsigned short* op = &o.x;
            #pragma unroll
            for (int j = 0; j < 4; ++j) {
                int k = kc * 4 + j;
                float v;
                if (k < 128) v = W[(size_t)k * 128 + n] + W[(size_t)(k + 128) * 128 + n];
                else         v = -W[(size_t)k * 128 + n];
                op[j] = f2bf(v);
            }
            *reinterpret_cast<ushort4*>(Wt + (size_t)n * 256 + kc * 4) = o;
        }
    }
}

// ---------------- scan + scatter (counting sort by dst) --------------------
__global__ void block_sum_kernel(const unsigned* __restrict__ counts,
                                 unsigned* __restrict__ bsums, int M) {
    int i = blockIdx.x * SBS + threadIdx.x;
    unsigned v = (i < M) ? counts[i] : 0u;
    for (int d = 32; d > 0; d >>= 1) v += __shfl_down(v, d);
    __shared__ unsigned ws[SBS / 64];
    int lane = threadIdx.x & 63, w = threadIdx.x >> 6;
    if (lane == 0) ws[w] = v;
    __syncthreads();
    if (threadIdx.x == 0) {
        unsigned s = 0;
        for (int k = 0; k < SBS / 64; ++k) s += ws[k];
        bsums[blockIdx.x] = s;
    }
}

__global__ void bsum_scan_kernel(const unsigned* __restrict__ bsums,
                                 unsigned* __restrict__ bbase, int NB,
                                 int* __restrict__ offsets, int M) {
    __shared__ unsigned s[256];
    int t = threadIdx.x;
    unsigned v = (t < NB) ? bsums[t] : 0u;
    s[t] = v;
    __syncthreads();
    for (int off = 1; off < 256; off <<= 1) {
        unsigned n = (t >= off) ? s[t - off] : 0u;
        __syncthreads();
        s[t] += n;
        __syncthreads();
    }
    if (t < NB) bbase[t] = s[t] - v;
    if (t == 255) offsets[M] = (int)s[255];
}

__global__ void scan_final_kernel(const unsigned* __restrict__ counts,
                                  const unsigned* __restrict__ bbase,
                                  int* __restrict__ offsets, int M) {
    int b = blockIdx.x, t = threadIdx.x;
    int i = b * SBS + t;
    unsigned c = (i < M) ? counts[i] : 0u;
    unsigned v = c;
    int lane = t & 63, w = t >> 6;
    for (int d = 1; d < 64; d <<= 1) {
        unsigned n = __shfl_up(v, d);
        if (lane >= d) v += n;
    }
    __shared__ unsigned ws[SBS / 64];
    if (lane == 63) ws[w] = v;
    __syncthreads();
    unsigned wbase = 0;
    for (int k = 0; k < w; ++k) wbase += ws[k];
    if (i < M) offsets[i] = (int)(bbase[b] + wbase + v - c);
}

__global__ void scatter_kernel(const int* __restrict__ e,
                               const int* __restrict__ offsets,
                               const int* __restrict__ rank,
                               int* __restrict__ csr, int E) {
    int i = blockIdx.x * blockDim.x + threadIdx.x;
    if (i < E) {
        int dst = e[E + i];
        csr[offsets[dst] + rank[i]] = e[i];
    }
}

// ---------------- Fused: LDS-idx gather-min + MFMA GEMM --------------------
// Block = 16 rows, 4 waves. Each wave: 4 rows, 16 lanes/row (uint4 = 8 cols).
// All 4 rows advance in ONE basic block (clamped duplicate edges, min-idem).
// A = [bf16(x_dst) | mn] in XOR-swizzled LDS; h^T = W't*A^T; out = xb+lrelu.
// M % FBM == 0.
template<int XSB>
__global__ __launch_bounds__(256, 4) void fused_kernel(
        const float* __restrict__ x_src,
        const unsigned short* __restrict__ xsb,
        const float* __restrict__ x_dst,
        const int* __restrict__ offsets,
        const int* __restrict__ csr,
        const unsigned short* __restrict__ Wt,
        const float* __restrict__ bias,
        float* __restrict__ out, int M) {
    __shared__ __align__(16) unsigned short At[FBM * 256];  // 8 KB
    __shared__ __align__(16) int eidx[ECAP];                // 2 KB
    __shared__ int offs[FBM + 1];
    char* Ab = reinterpret_cast<char*>(At);
    int tid = threadIdx.x;
    int lane = tid & 63;
    int wv = tid >> 6;
    int blockRow = blockIdx.x * FBM;

    // ---- stage: offsets slice, xb tile, csr slice (one barrier) ----
    int ebeg = offsets[blockRow];
    int eend = offsets[blockRow + FBM];
    int ecount = eend - ebeg;
    if (tid <= FBM) offs[tid] = offsets[blockRow + tid];
    #pragma unroll
    for (int i = 0; i < FBM * 32 / 256; ++i) {   // 2 float4 per thread
        int u = tid + 256 * i;
        int lr = u >> 5, c4 = u & 31;
        float4 v = reinterpret_cast<const float4*>(x_dst)[(size_t)(blockRow + lr) * 32 + c4];
        ushort4 o;
        o.x = f2bf(v.x); o.y = f2bf(v.y); o.z = f2bf(v.z); o.w = f2bf(v.w);
        *reinterpret_cast<ushort4*>(Ab + swz(lr, c4 * 8)) = o;
    }
    bool fit = (ecount <= ECAP);
    for (int i = tid; i < min(ecount, ECAP); i += 256) eidx[i] = csr[ebeg + i];
    __syncthreads();

    // ---- gather-min: lane = (row rg, col-block l15); 4 edges/row/batch ----
    int l15 = lane & 15;
    int rg = lane >> 4;
    int lr = wv * 4 + rg;
    int rb = offs[lr] - ebeg;
    int re = offs[lr + 1] - ebeg;
    int deg = re - rb;
    int lim = re - 1;                       // may be rb-1 when deg==0
    int oA = offs[wv * 4], oB = offs[wv * 4 + 1], oC = offs[wv * 4 + 2];
    int oD = offs[wv * 4 + 3], oE = offs[wv * 4 + 4];
    int mb = max(max(oB - oA, oC - oB), max(oD - oC, oE - oD));
    int nb4 = ((mb + 3) >> 2) << 2;         // wave-uniform batch bound

    float mn[8];
    #pragma unroll
    for (int j = 0; j < 8; ++j) mn[j] = INFINITY;

#define GLOOP(IDX)                                                          \
    for (int e0 = 0; e0 < nb4; e0 += 4) {                                   \
        int p0 = max(min(rb + e0 + 0, lim), 0);                             \
        int p1 = max(min(rb + e0 + 1, lim), 0);                             \
        int p2 = max(min(rb + e0 + 2, lim), 0);                             \
        int p3 = max(min(rb + e0 + 3, lim), 0);                             \
        int i0 = IDX(p0); int i1 = IDX(p1); int i2 = IDX(p2); int i3 = IDX(p3); \
        if (XSB) {                                                          \
            const uint4* xs = reinterpret_cast<const uint4*>(xsb);          \
            uint4 v0 = xs[(size_t)i0 * 16 + l15];                           \
            uint4 v1 = xs[(size_t)i1 * 16 + l15];                           \
            uint4 v2 = xs[(size_t)i2 * 16 + l15];                           \
            uint4 v3 = xs[(size_t)i3 * 16 + l15];                           \
            fmin8u(mn, v0); fmin8u(mn, v1); fmin8u(mn, v2); fmin8u(mn, v3); \
        } else {                                                            \
            const float4* xf = reinterpret_cast<const float4*>(x_src);      \
            float4 a0 = xf[(size_t)i0 * 32 + l15 * 2];                      \
            float4 b0 = xf[(size_t)i0 * 32 + l15 * 2 + 1];                  \
            float4 a1 = xf[(size_t)i1 * 32 + l15 * 2];                      \
            float4 b1 = xf[(size_t)i1 * 32 + l15 * 2 + 1];                  \
            float4 a2 = xf[(size_t)i2 * 32 + l15 * 2];                      \
            float4 b2 = xf[(size_t)i2 * 32 + l15 * 2 + 1];                  \
            float4 a3 = xf[(size_t)i3 * 32 + l15 * 2];                      \
            float4 b3 = xf[(size_t)i3 * 32 + l15 * 2 + 1];                  \
            a0.x = fminf(a0.x, a1.x); a0.y = fminf(a0.y, a1.y);             \
            a0.z = fminf(a0.z, a1.z); a0.w = fminf(a0.w, a1.w);             \
            a2.x = fminf(a2.x, a3.x); a2.y = fminf(a2.y, a3.y);             \
            a2.z = fminf(a2.z, a3.z); a2.w = fminf(a2.w, a3.w);             \
            mn[0] = fminf(mn[0], fminf(a0.x, a2.x));                        \
            mn[1] = fminf(mn[1], fminf(a0.y, a2.y));                        \
            mn[2] = fminf(mn[2], fminf(a0.z, a2.z));                        \
            mn[3] = fminf(mn[3], fminf(a0.w, a2.w));                        \
            b0.x = fminf(b0.x, b1.x); b0.y = fminf(b0.y, b1.y);             \
            b0.z = fminf(b0.z, b1.z); b0.w = fminf(b0.w, b1.w);             \
            b2.x = fminf(b2.x, b3.x); b2.y = fminf(b2.y, b3.y);             \
            b2.z = fminf(b2.z, b3.z); b2.w = fminf(b2.w, b3.w);             \
            mn[4] = fminf(mn[4], fminf(b0.x, b2.x));                        \
            mn[5] = fminf(mn[5], fminf(b0.y, b2.y));                        \
            mn[6] = fminf(mn[6], fminf(b0.z, b2.z));                        \
            mn[7] = fminf(mn[7], fminf(b0.w, b2.w));                        \
        }                                                                   \
    }

#define IDX_LDS(p) eidx[p]
#define IDX_GLB(p) csr[ebeg + (p)]
    if (fit) { GLOOP(IDX_LDS) } else { GLOOP(IDX_GLB) }
#undef IDX_LDS
#undef IDX_GLB
#undef GLOOP

    // ---- write mn half of A (this lane owns row lr, cols l15*8..+7) ----
    {
        ushort4 oa, ob;
        if (deg > 0) {
            oa.x = f2bf(mn[0]); oa.y = f2bf(mn[1]);
            oa.z = f2bf(mn[2]); oa.w = f2bf(mn[3]);
            ob.x = f2bf(mn[4]); ob.y = f2bf(mn[5]);
            ob.z = f2bf(mn[6]); ob.w = f2bf(mn[7]);
        } else {   // empty row: mn := xb  =>  h = xb@W0 exactly
            oa = *reinterpret_cast<const ushort4*>(Ab + swz(lr, l15 * 16));
            ob = *reinterpret_cast<const ushort4*>(Ab + swz(lr, l15 * 16 + 8));
        }
        *reinterpret_cast<ushort4*>(Ab + swz(lr, 256 + l15 * 16)) = oa;
        *reinterpret_cast<ushort4*>(Ab + swz(lr, 256 + l15 * 16 + 8)) = ob;
    }
    __syncthreads();

    // ---- MFMA GEMM: A (16x256) from LDS, B (folded W') from L2 ----
    int q = lane >> 4;
    int ncol0 = wv * 32;
    f32x4 acc0 = (f32x4){0.f, 0.f, 0.f, 0.f};
    f32x4 acc1 = (f32x4){0.f, 0.f, 0.f, 0.f};
    size_t b0off = (size_t)(ncol0 + l15) * 256;
    size_t b1off = (size_t)(ncol0 + 16 + l15) * 256;

    #pragma unroll
    for (int s = 0; s < 8; ++s) {
        int koff = s * 32 + q * 8;               // bf16 elements
        short8 b0 = *reinterpret_cast<const short8*>(Wt + b0off + koff);
        short8 b1 = *reinterpret_cast<const short8*>(Wt + b1off + koff);
        short8 a = *reinterpret_cast<const short8*>(Ab + swz(l15, koff * 2));
        // swapped operands: C col(lane&15)=out row, C row(q*4+reg)=out col
        acc0 = __builtin_amdgcn_mfma_f32_16x16x32_bf16(b0, a, acc0, 0, 0, 0);
        acc1 = __builtin_amdgcn_mfma_f32_16x16x32_bf16(b1, a, acc1, 0, 0, 0);
    }

    float4 bi0 = *reinterpret_cast<const float4*>(bias + ncol0 + q * 4);
    float4 bi1 = *reinterpret_cast<const float4*>(bias + ncol0 + 16 + q * 4);
    int row = blockRow + l15;                    // M % 16 == 0: always valid
    #pragma unroll
    for (int u = 0; u < 2; ++u) {
        int col = ncol0 + u * 16 + q * 4;
        f32x4 av = u ? acc1 : acc0;
        float4 bv = u ? bi1 : bi0;
        uint2 xu = *reinterpret_cast<const uint2*>(Ab + swz(l15, col * 2));
        float4 xb = upk(xu);
        float4 o;
        float h;
        h = av[0] + bv.x; o.x = xb.x + (h > 0.f ? h : SLOPE * h);
        h = av[1] + bv.y; o.y = xb.y + (h > 0.f ? h : SLOPE * h);
        h = av[2] + bv.z; o.z = xb.z + (h > 0.f ? h : SLOPE * h);
        h = av[3] + bv.w; o.w = xb.w + (h > 0.f ? h : SLOPE * h);
        *reinterpret_cast<float4*>(out + (size_t)row * 128 + col) = o;
    }
}

extern "C" void kernel_launch(void* const* d_in, const int* in_sizes, int n_in,
                              void* d_out, int out_size, void* d_ws, size_t ws_size,
                              hipStream_t stream) {
    const float* x_src = (const float*)d_in[0];
    const float* x_dst = (const float*)d_in[1];
    const int*   e     = (const int*)d_in[2];
    const float* W     = (const float*)d_in[3];
    const float* bias  = (const float*)d_in[4];
    float* out = (float*)d_out;

    int NS = in_sizes[0] / WIDTH;   // 100000 src nodes
    int E  = in_sizes[2] / 2;       // 800000
    int M  = in_sizes[1] / WIDTH;   // 100000 dst nodes
    int NB = (M + SBS - 1) / SBS;   // 196 (<= 256)

    // ws: xsb bf16[NS*128] | Wt bf16[128*256] | counts[M] | offsets[M+1] |
    //     rank[E] | csr[E] | bsums[NB] | bbase[NB]    (~33 MB)
    unsigned short* xsb = (unsigned short*)d_ws;
    unsigned short* Wt  = xsb + (size_t)NS * WIDTH;
    unsigned* counts  = (unsigned*)(Wt + 128 * 256);
    int*      offsets = (int*)(counts + M);
    int*      rank    = offsets + (M + 1);
    int*      csr     = rank + E;
    unsigned* bsums   = (unsigned*)(csr + E);
    unsigned* bbase   = bsums + NB;
    size_t need = (char*)(bbase + NB) - (char*)d_ws;
    int use_xsb = (ws_size >= need) ? 1 : 0;
    if (!use_xsb) {   // fallback: no xsb; shift layout to skip it
        Wt = (unsigned short*)d_ws;
        counts  = (unsigned*)(Wt + 128 * 256);
        offsets = (int*)(counts + M);
        rank    = offsets + (M + 1);
        csr     = rank + E;
        bsums   = (unsigned*)(csr + E);
        bbase   = bsums + NB;
    }

    hipMemsetAsync(counts, 0, (size_t)M * sizeof(unsigned), stream);

    int nconv = use_xsb ? (NS * 32 + 255) / 256 : 0;
    int nhist = (E + 255) / 256;
    int nwt   = (128 * 64 + 255) / 256;
    prep_kernel<<<nconv + nhist + nwt, 256, 0, stream>>>(x_src, W, e, xsb, Wt,
                                                         counts, rank, NS, E,
                                                         nconv, nhist);
    block_sum_kernel<<<NB, SBS, 0, stream>>>(counts, bsums, M);
    bsum_scan_kernel<<<1, 256, 0, stream>>>(bsums, bbase, NB, offsets, M);
    scan_final_kernel<<<NB, SBS, 0, stream>>>(counts, bbase, offsets, M);
    scatter_kernel<<<(E + 255) / 256, 256, 0, stream>>>(e, offsets, rank, csr, E);

    int fblocks = (M + FBM - 1) / FBM;   // 6250
    if (use_xsb)
        fused_kernel<1><<<fblocks, 256, 0, stream>>>(x_src, xsb, x_dst, offsets,
                                                     csr, Wt, bias, out, M);
    else
        fused_kernel<0><<<fblocks, 256, 0, stream>>>(x_src, xsb, x_dst, offsets,
                                                     csr, Wt, bias, out, M);
}